// Round 6
// baseline (252.687 us; speedup 1.0000x reference)
//
#include <hip/hip_runtime.h>
#include <cstddef>

#define NB   16
#define CIN  512
#define NTOK 1600   // 40*40
#define HCH  64
#define LDA  72     // padded LDS row stride (bf16 elems), mult of 8 for 16B loads

typedef __attribute__((ext_vector_type(8))) short bf16x8;
typedef __attribute__((ext_vector_type(4))) float f32x4;

__device__ __forceinline__ unsigned short f2bf(float x) {
    union { float f; unsigned u; } v; v.f = x;
    unsigned r = v.u + 0x7FFFu + ((v.u >> 16) & 1u);   // round-nearest-even
    return (unsigned short)(r >> 16);
}

__device__ __forceinline__ unsigned cvtpk_bf16(float lo, float hi) {
    unsigned r;
    asm("v_cvt_pk_bf16_f32 %0, %1, %2" : "=v"(r) : "v"(lo), "v"(hi));
    return r;
}

__device__ __forceinline__ float fast_exp2(float x) {
#if __has_builtin(__builtin_amdgcn_exp2f)
    return __builtin_amdgcn_exp2f(x);
#else
    return exp2f(x);
#endif
}

// ---------------------------------------------------------------------------
// Weight prep: Wt[3][64h][512c] = {wq,wk,wv}^T ; WoT[512c][64j] = wo^T
// ---------------------------------------------------------------------------
__global__ void __launch_bounds__(256) wprep_kernel(
    const float* __restrict__ wq, const float* __restrict__ wk,
    const float* __restrict__ wv, const float* __restrict__ wo,
    unsigned short* __restrict__ Wt, unsigned short* __restrict__ WoT)
{
    const int gid = blockIdx.x * 256 + threadIdx.x;
    if (gid < 3 * HCH * (CIN / 8)) {               // 12288 Wt threads
        const int h  = gid & 63;
        const int c8 = (gid >> 6) & 63;
        const int t  = gid >> 12;
        const float* w = (t == 0) ? wq : (t == 1) ? wk : wv;
        ushort4 lo, hi;
        lo.x = f2bf(w[(size_t)(c8 * 8 + 0) * HCH + h]);
        lo.y = f2bf(w[(size_t)(c8 * 8 + 1) * HCH + h]);
        lo.z = f2bf(w[(size_t)(c8 * 8 + 2) * HCH + h]);
        lo.w = f2bf(w[(size_t)(c8 * 8 + 3) * HCH + h]);
        hi.x = f2bf(w[(size_t)(c8 * 8 + 4) * HCH + h]);
        hi.y = f2bf(w[(size_t)(c8 * 8 + 5) * HCH + h]);
        hi.z = f2bf(w[(size_t)(c8 * 8 + 6) * HCH + h]);
        hi.w = f2bf(w[(size_t)(c8 * 8 + 7) * HCH + h]);
        ushort4* dst = (ushort4*)(Wt + ((size_t)t * HCH + h) * CIN + c8 * 8);
        dst[0] = lo; dst[1] = hi;
    } else {                                        // 4096 WoT threads
        const int g  = gid - 3 * HCH * (CIN / 8);
        const int c  = g & 511;
        const int j8 = g >> 9;
        ushort4 lo, hi;
        lo.x = f2bf(wo[(size_t)(j8 * 8 + 0) * CIN + c]);
        lo.y = f2bf(wo[(size_t)(j8 * 8 + 1) * CIN + c]);
        lo.z = f2bf(wo[(size_t)(j8 * 8 + 2) * CIN + c]);
        lo.w = f2bf(wo[(size_t)(j8 * 8 + 3) * CIN + c]);
        hi.x = f2bf(wo[(size_t)(j8 * 8 + 4) * CIN + c]);
        hi.y = f2bf(wo[(size_t)(j8 * 8 + 5) * CIN + c]);
        hi.z = f2bf(wo[(size_t)(j8 * 8 + 6) * CIN + c]);
        hi.w = f2bf(wo[(size_t)(j8 * 8 + 7) * CIN + c]);
        ushort4* dst = (ushort4*)(WoT + (size_t)c * HCH + j8 * 8);
        dst[0] = lo; dst[1] = hi;
    }
}

// ---------------------------------------------------------------------------
// Projections (MFMA). blockIdx.y==0: Q,K from rgb; ==1: V from hsi.
// Q is pre-scaled by 0.125/ln(2) so attention can use raw exp2.
// Q,K stored [b][n][h]; V stored Vt[b][h][perm(n)] where perm permutes keys
// within each 64-token tile so attention's P pack is fully lane-local:
//   n6 = g*16 + q4*4 + r  ->  p6 = (g&1)*32 + q4*8 + (g>>1)*4 + r
// As staging uses a chunk-XOR swizzle (chunk' = chunk ^ ((n>>1)&6)) to make
// the b16 transpose writes bank-conflict-free; reads apply the same XOR.
// ---------------------------------------------------------------------------
__global__ void __launch_bounds__(256) proj_kernel(
    const float* __restrict__ rgb, const float* __restrict__ hsi,
    const unsigned short* __restrict__ Wt,
    unsigned short* __restrict__ Q, unsigned short* __restrict__ K,
    unsigned short* __restrict__ Vt)
{
    __shared__ __align__(16) unsigned short As[64 * LDA];
    __shared__ __align__(16) unsigned short Ws[128 * LDA];

    const int which = blockIdx.y;                 // 0: QK, 1: V
    const int b    = blockIdx.x / 25;
    const int n0   = (blockIdx.x % 25) * 64;
    const int tid  = threadIdx.x;
    const int wv_  = tid >> 6;
    const int lane = tid & 63;
    const int l16  = lane & 15, quad = lane >> 4;

    const float* __restrict__ src = which ? hsi : rgb;
    const unsigned short* __restrict__ wbase = Wt + (which ? (size_t)2 * HCH * CIN : 0);
    const int nW = which ? 1 : 2;

    f32x4 acc[2][4];
    #pragma unroll
    for (int t = 0; t < 2; ++t)
        #pragma unroll
        for (int nt = 0; nt < 4; ++nt)
            #pragma unroll
            for (int r = 0; r < 4; ++r) acc[t][nt][r] = 0.f;

    const int cc = tid >> 2;           // 0..63 channel row (staging)
    const int nq = tid & 3;
    const int swz = cc >> 3;           // channel chunk 0..7
    const int clo = cc & 7;
    const int swzr = (l16 >> 1) & 6;   // read-side XOR (row = wv_*16+l16; wv_*16 ≡ 0 mod 8)

    for (int c0 = 0; c0 < CIN; c0 += 64) {
        __syncthreads();
        {   // token tile transpose f32 -> bf16, [n][c] c-minor, chunk-swizzled
            const float* gs = src + ((size_t)b * CIN + c0 + cc) * NTOK + n0;
            #pragma unroll
            for (int rep = 0; rep < 4; ++rep) {
                const int nn4 = rep * 4 + nq;
                const float4 a = ((const float4*)gs)[nn4];
                const int n = nn4 * 4;
                const int i01 = ((swz ^ ((n >> 1) & 6)) << 3) + clo;
                const int i23 = ((swz ^ (((n + 2) >> 1) & 6)) << 3) + clo;
                As[(n + 0) * LDA + i01] = f2bf(a.x);
                As[(n + 1) * LDA + i01] = f2bf(a.y);
                As[(n + 2) * LDA + i23] = f2bf(a.z);
                As[(n + 3) * LDA + i23] = f2bf(a.w);
            }
        }
        for (int task = tid; task < nW * 512; task += 256) {
            const int row = task >> 3, ch = task & 7;
            *((int4*)(Ws + row * LDA + ch * 8)) =
                *((const int4*)(wbase + (size_t)row * CIN + c0 + ch * 8));
        }
        __syncthreads();

        #pragma unroll
        for (int k0 = 0; k0 < 2; ++k0) {
            const bf16x8 av = *((const bf16x8*)(As + (wv_ * 16 + l16) * LDA + ((k0 * 4 + quad) ^ swzr) * 8));
            if (which == 0) {
                #pragma unroll
                for (int t = 0; t < 2; ++t)
                    #pragma unroll
                    for (int nt = 0; nt < 4; ++nt) {
                        const bf16x8 bv = *((const bf16x8*)(Ws + (t * 64 + nt * 16 + l16) * LDA + k0 * 32 + quad * 8));
                        acc[t][nt] = __builtin_amdgcn_mfma_f32_16x16x32_bf16(av, bv, acc[t][nt], 0, 0, 0);
                    }
            } else {
                #pragma unroll
                for (int nt = 0; nt < 4; ++nt) {
                    const bf16x8 bv = *((const bf16x8*)(Ws + (nt * 16 + l16) * LDA + k0 * 32 + quad * 8));
                    acc[0][nt] = __builtin_amdgcn_mfma_f32_16x16x32_bf16(av, bv, acc[0][nt], 0, 0, 0);
                }
            }
        }
    }

    if (which == 0) {
        const float qscale = 0.18033688f;          // 0.125 / ln(2)
        #pragma unroll
        for (int nt = 0; nt < 4; ++nt) {
            const int h = nt * 16 + l16;
            #pragma unroll
            for (int r = 0; r < 4; ++r) {
                const int n = n0 + wv_ * 16 + quad * 4 + r;
                Q[((size_t)b * NTOK + n) * HCH + h] = f2bf(acc[0][nt][r] * qscale);
                K[((size_t)b * NTOK + n) * HCH + h] = f2bf(acc[1][nt][r]);
            }
        }
    } else {
        // permuted V store: keys n0 + wv_*16 + quad*4 + (0..3)  (g = wv_, q4 = quad)
        // go to positions n0 + (wv_&1)*32 + quad*8 + (wv_>>1)*4 + (0..3)
        const int pbase = n0 + (wv_ & 1) * 32 + quad * 8 + (wv_ >> 1) * 4;
        #pragma unroll
        for (int nt = 0; nt < 4; ++nt) {
            const int h = nt * 16 + l16;
            ushort4 pv;
            pv.x = f2bf(acc[0][nt][0]); pv.y = f2bf(acc[0][nt][1]);
            pv.z = f2bf(acc[0][nt][2]); pv.w = f2bf(acc[0][nt][3]);
            *((ushort4*)(Vt + ((size_t)b * HCH + h) * NTOK + pbase)) = pv;
        }
    }
}

// ---------------------------------------------------------------------------
// Attention helpers (16-query per-wave slice; compute verified in R4).
// ---------------------------------------------------------------------------
__device__ __forceinline__ void attn_load_k(
    const unsigned short* __restrict__ Kg, int kt, int l16, int quad,
    bf16x8 (&kb)[2][4])
{
    #pragma unroll
    for (int k0 = 0; k0 < 2; ++k0)
        #pragma unroll
        for (int nt = 0; nt < 4; ++nt)
            kb[k0][nt] = *((const bf16x8*)(Kg + ((size_t)(kt * 64 + nt * 16 + l16)) * HCH + k0 * 32 + quad * 8));
}

__device__ __forceinline__ void attn_load_v(
    const unsigned short* __restrict__ Vg, int kt, int l16, int quad,
    bf16x8 (&vb)[2][4])
{
    #pragma unroll
    for (int k0 = 0; k0 < 2; ++k0)
        #pragma unroll
        for (int nt = 0; nt < 4; ++nt)
            vb[k0][nt] = *((const bf16x8*)(Vg + ((size_t)(nt * 16 + l16)) * NTOK + kt * 64 + k0 * 32 + quad * 8));
}

__device__ __forceinline__ void attn_compute_tile(
    const bf16x8 (&kb)[2][4], const bf16x8 (&vb)[2][4],
    const bf16x8 (&qa)[2], f32x4 (&o)[4], float& rs)
{
    // ---- S^T = K Q^T : col = q (l16), row = key (quad*4+r) ----
    f32x4 s[4];
    #pragma unroll
    for (int nt = 0; nt < 4; ++nt)
        #pragma unroll
        for (int r = 0; r < 4; ++r) s[nt][r] = 0.f;
    #pragma unroll
    for (int k0 = 0; k0 < 2; ++k0)
        #pragma unroll
        for (int nt = 0; nt < 4; ++nt)
            s[nt] = __builtin_amdgcn_mfma_f32_16x16x32_bf16(kb[k0][nt], qa[k0], s[nt], 0, 0, 0);

    // ---- P = exp2(S^T) in-lane, pack bf16 pairs, accumulate row sums ----
    unsigned dA[4], dB[4];
    #pragma unroll
    for (int nt = 0; nt < 4; ++nt) {
        const float e0 = fast_exp2(s[nt][0]);
        const float e1 = fast_exp2(s[nt][1]);
        const float e2 = fast_exp2(s[nt][2]);
        const float e3 = fast_exp2(s[nt][3]);
        rs += (e0 + e1) + (e2 + e3);
        dA[nt] = cvtpk_bf16(e0, e1);
        dB[nt] = cvtpk_bf16(e2, e3);
    }

    // ---- O += P V (V stored pre-permuted to match this packing) ----
    #pragma unroll
    for (int k0 = 0; k0 < 2; ++k0) {
        union { bf16x8 v; unsigned u[4]; } pu;
        pu.u[0] = dA[k0];
        pu.u[1] = dB[k0];
        pu.u[2] = dA[k0 + 2];
        pu.u[3] = dB[k0 + 2];
        #pragma unroll
        for (int nt = 0; nt < 4; ++nt)
            o[nt] = __builtin_amdgcn_mfma_f32_16x16x32_bf16(pu.v, vb[k0][nt], o[nt], 0, 0, 0);
    }
}

// ---------------------------------------------------------------------------
// Attention, no-max softmax (exp2, scale pre-folded into Q), split-Q.
// Block = 64 queries, 4 waves; wave w owns queries [qt*64+w*16, +16) and
// walks ALL 25 k-tiles (no split-K -> no merge, no LDS, no barriers).
// All 4 waves load IDENTICAL K/V addresses: first wave misses to L2, the
// rest hit L1 (16 KB tile < 32 KB L1). K is register double-buffered
// (prefetch t+1 before compute t); V single-buffered, issued at compute
// top so its latency hides under QK^T+softmax. Per-wave state is small
// (qa 16 + o 16 + s 16 regs) so the pipeline fits without spills.
// blockIdx swizzle: XCD k hosts batches {2k, 2k+1} (800 KB < 4 MB L2).
// ---------------------------------------------------------------------------
__global__ void __launch_bounds__(256, 2) attn_kernel(
    const unsigned short* __restrict__ Q, const unsigned short* __restrict__ K,
    const unsigned short* __restrict__ Vt, unsigned short* __restrict__ Rt2)
{
    const int bx   = blockIdx.x;                // 0..399
    const int b    = 2 * (bx & 7) + (((bx >> 3) >= 25) ? 1 : 0);
    const int qt   = (bx >> 3) % 25;            // 64-query tile
    const int tid  = threadIdx.x;
    const int wv_  = tid >> 6;
    const int lane = tid & 63;
    const int l16  = lane & 15, quad = lane >> 4;

    const unsigned short* Qg = Q  + ((size_t)b * NTOK + qt * 64 + wv_ * 16) * HCH;
    const unsigned short* Kg = K  + (size_t)b * NTOK * HCH;
    const unsigned short* Vg = Vt + (size_t)b * HCH * NTOK;

    // Q fragments (B-operand of the swapped QK^T), resident all kernel
    bf16x8 qa[2];
    #pragma unroll
    for (int k0 = 0; k0 < 2; ++k0)
        qa[k0] = *((const bf16x8*)(Qg + (size_t)l16 * HCH + k0 * 32 + quad * 8));

    f32x4 o[4];
    float rs = 0.f;
    #pragma unroll
    for (int nt = 0; nt < 4; ++nt)
        #pragma unroll
        for (int r = 0; r < 4; ++r) o[nt][r] = 0.f;

    // ---- K-dbuf software pipeline over all 25 tiles ----
    bf16x8 kbA[2][4], kbB[2][4], vb[2][4];
    attn_load_k(Kg, 0, l16, quad, kbA);
    int kt = 0;
    while (true) {
        attn_load_v(Vg, kt, l16, quad, vb);
        if (kt + 1 < 25) attn_load_k(Kg, kt + 1, l16, quad, kbB);
        attn_compute_tile(kbA, vb, qa, o, rs);
        ++kt; if (kt >= 25) break;
        attn_load_v(Vg, kt, l16, quad, vb);
        if (kt + 1 < 25) attn_load_k(Kg, kt + 1, l16, quad, kbA);
        attn_compute_tile(kbB, vb, qa, o, rs);
        ++kt; if (kt >= 25) break;
    }

    // ---- complete row sums (q = l16) across the 4 quads ----
    rs += __shfl_xor(rs, 16);
    rs += __shfl_xor(rs, 32);
    // redistribute to o's q layout (q = quad*4 + r): source lanes 0..15
    float rsq[4];
    #pragma unroll
    for (int r = 0; r < 4; ++r) rsq[r] = __shfl(rs, quad * 4 + r);

    // ---- direct output: Rt2[b][t=qt][h=nt*16+l16][j=wv_*16+quad*4+r] ----
    unsigned short* Rg = Rt2 + ((size_t)(b * 25 + qt)) * HCH * HCH;
    #pragma unroll
    for (int nt = 0; nt < 4; ++nt) {
        ushort4 pk;
        pk.x = f2bf(o[nt][0] / rsq[0]);
        pk.y = f2bf(o[nt][1] / rsq[1]);
        pk.z = f2bf(o[nt][2] / rsq[2]);
        pk.w = f2bf(o[nt][3] / rsq[3]);
        *((ushort4*)(Rg + (size_t)(nt * 16 + l16) * HCH + wv_ * 16 + quad * 4)) = pk;
    }
}

// ---------------------------------------------------------------------------
// Output projection: out[b][c][h*25+t] = sum_j wo[j][c] * Rt2[b][t][h][j]
// Grid (16 b, 8 c-tiles, 25 n-tiles): one 64x64 output tile per block.
// ---------------------------------------------------------------------------
__global__ void __launch_bounds__(256) outproj_kernel(
    const unsigned short* __restrict__ Rt2, const unsigned short* __restrict__ WoT,
    float* __restrict__ out)
{
    __shared__ __align__(16) unsigned short Aw[64 * LDA];

    const int b    = blockIdx.x;
    const int ct   = blockIdx.y;
    const int nt64 = blockIdx.z;
    const int tid  = threadIdx.x;
    const int wv_  = tid >> 6;
    const int lane = tid & 63;
    const int l16  = lane & 15, quad = lane >> 4;

    #pragma unroll
    for (int r = 0; r < 2; ++r) {
        const int task = tid + r * 256;
        const int row = task >> 3, ch = task & 7;
        *((int4*)(Aw + row * LDA + ch * 8)) =
            *((const int4*)(WoT + ((size_t)(ct * 64 + row)) * HCH + ch * 8));
    }
    __syncthreads();

    const int n = nt64 * 64 + wv_ * 16 + l16;
    const int h = n / 25, t = n % 25;
    const unsigned short* bsrc = Rt2 + ((size_t)(b * 25 + t) * HCH + h) * HCH;

    f32x4 acc[4];
    #pragma unroll
    for (int mt = 0; mt < 4; ++mt)
        #pragma unroll
        for (int r = 0; r < 4; ++r) acc[mt][r] = 0.f;

    #pragma unroll
    for (int k0 = 0; k0 < 2; ++k0) {
        const bf16x8 bv = *((const bf16x8*)(bsrc + k0 * 32 + quad * 8));
        #pragma unroll
        for (int mt = 0; mt < 4; ++mt) {
            const bf16x8 av = *((const bf16x8*)(Aw + (mt * 16 + l16) * LDA + k0 * 32 + quad * 8));
            acc[mt] = __builtin_amdgcn_mfma_f32_16x16x32_bf16(av, bv, acc[mt], 0, 0, 0);
        }
    }
    #pragma unroll
    for (int mt = 0; mt < 4; ++mt)
        #pragma unroll
        for (int r = 0; r < 4; ++r)
            out[((size_t)b * CIN + ct * 64 + mt * 16 + quad * 4 + r) * NTOK + n] = acc[mt][r];
}

// ---------------------------------------------------------------------------
extern "C" void kernel_launch(void* const* d_in, const int* in_sizes, int n_in,
                              void* d_out, int out_size, void* d_ws, size_t ws_size,
                              hipStream_t stream)
{
    const float* rgb = (const float*)d_in[0];
    const float* hsi = (const float*)d_in[1];
    const float* wq  = (const float*)d_in[2];
    const float* wk  = (const float*)d_in[3];
    const float* wv  = (const float*)d_in[4];
    const float* wo  = (const float*)d_in[5];
    float* out = (float*)d_out;

    unsigned short* Wt  = (unsigned short*)d_ws;
    unsigned short* WoT = Wt  + (size_t)3 * HCH * CIN;
    unsigned short* Qb  = WoT + (size_t)CIN * HCH;
    unsigned short* Kb  = Qb  + (size_t)NB * NTOK * HCH;
    unsigned short* Vtb = Kb  + (size_t)NB * NTOK * HCH;
    unsigned short* Rt2 = Vtb + (size_t)NB * NTOK * HCH;

    wprep_kernel<<<dim3(64), 256, 0, stream>>>(wq, wk, wv, wo, Wt, WoT);
    proj_kernel<<<dim3(NB * 25, 2), 256, 0, stream>>>(rgb, hsi, Wt, Qb, Kb, Vtb);
    attn_kernel<<<dim3(NB * 25), 256, 0, stream>>>(Qb, Kb, Vtb, Rt2);
    outproj_kernel<<<dim3(NB, 8, 25), 256, 0, stream>>>(Rt2, WoT, out);
}

// Round 7
// 184.634 us; speedup vs baseline: 1.3686x; 1.3686x over previous
//
#include <hip/hip_runtime.h>
#include <cstddef>

#define NB   16
#define CIN  512
#define NTOK 1600   // 40*40
#define HCH  64
#define LDA  72     // padded LDS row stride (bf16 elems), mult of 8 for 16B loads

typedef __attribute__((ext_vector_type(8))) short bf16x8;
typedef __attribute__((ext_vector_type(4))) float f32x4;

__device__ __forceinline__ unsigned short f2bf(float x) {
    union { float f; unsigned u; } v; v.f = x;
    unsigned r = v.u + 0x7FFFu + ((v.u >> 16) & 1u);   // round-nearest-even
    return (unsigned short)(r >> 16);
}

__device__ __forceinline__ unsigned cvtpk_bf16(float lo, float hi) {
    unsigned r;
    asm("v_cvt_pk_bf16_f32 %0, %1, %2" : "=v"(r) : "v"(lo), "v"(hi));
    return r;
}

__device__ __forceinline__ float fast_exp2(float x) {
#if __has_builtin(__builtin_amdgcn_exp2f)
    return __builtin_amdgcn_exp2f(x);
#else
    return exp2f(x);
#endif
}

// ---------------------------------------------------------------------------
// Weight prep: Wt[3][64h][512c] = {wq,wk,wv}^T ; WoT[512c][64j] = wo^T
// ---------------------------------------------------------------------------
__global__ void __launch_bounds__(256) wprep_kernel(
    const float* __restrict__ wq, const float* __restrict__ wk,
    const float* __restrict__ wv, const float* __restrict__ wo,
    unsigned short* __restrict__ Wt, unsigned short* __restrict__ WoT)
{
    const int gid = blockIdx.x * 256 + threadIdx.x;
    if (gid < 3 * HCH * (CIN / 8)) {               // 12288 Wt threads
        const int h  = gid & 63;
        const int c8 = (gid >> 6) & 63;
        const int t  = gid >> 12;
        const float* w = (t == 0) ? wq : (t == 1) ? wk : wv;
        ushort4 lo, hi;
        lo.x = f2bf(w[(size_t)(c8 * 8 + 0) * HCH + h]);
        lo.y = f2bf(w[(size_t)(c8 * 8 + 1) * HCH + h]);
        lo.z = f2bf(w[(size_t)(c8 * 8 + 2) * HCH + h]);
        lo.w = f2bf(w[(size_t)(c8 * 8 + 3) * HCH + h]);
        hi.x = f2bf(w[(size_t)(c8 * 8 + 4) * HCH + h]);
        hi.y = f2bf(w[(size_t)(c8 * 8 + 5) * HCH + h]);
        hi.z = f2bf(w[(size_t)(c8 * 8 + 6) * HCH + h]);
        hi.w = f2bf(w[(size_t)(c8 * 8 + 7) * HCH + h]);
        ushort4* dst = (ushort4*)(Wt + ((size_t)t * HCH + h) * CIN + c8 * 8);
        dst[0] = lo; dst[1] = hi;
    } else {                                        // 4096 WoT threads
        const int g  = gid - 3 * HCH * (CIN / 8);
        const int c  = g & 511;
        const int j8 = g >> 9;
        ushort4 lo, hi;
        lo.x = f2bf(wo[(size_t)(j8 * 8 + 0) * CIN + c]);
        lo.y = f2bf(wo[(size_t)(j8 * 8 + 1) * CIN + c]);
        lo.z = f2bf(wo[(size_t)(j8 * 8 + 2) * CIN + c]);
        lo.w = f2bf(wo[(size_t)(j8 * 8 + 3) * CIN + c]);
        hi.x = f2bf(wo[(size_t)(j8 * 8 + 4) * CIN + c]);
        hi.y = f2bf(wo[(size_t)(j8 * 8 + 5) * CIN + c]);
        hi.z = f2bf(wo[(size_t)(j8 * 8 + 6) * CIN + c]);
        hi.w = f2bf(wo[(size_t)(j8 * 8 + 7) * CIN + c]);
        ushort4* dst = (ushort4*)(WoT + (size_t)c * HCH + j8 * 8);
        dst[0] = lo; dst[1] = hi;
    }
}

// ---------------------------------------------------------------------------
// Projections (MFMA). blockIdx.y==0: Q,K from rgb; ==1: V from hsi.
// Q is pre-scaled by 0.125/ln(2) so attention can use raw exp2.
// Q,K stored [b][n][h]; V stored Vt[b][h][perm(n)] where perm permutes keys
// within each 64-token tile so attention's P pack is fully lane-local:
//   n6 = g*16 + q4*4 + r  ->  p6 = (g&1)*32 + q4*8 + (g>>1)*4 + r
// As staging uses a chunk-XOR swizzle (chunk' = chunk ^ ((n>>1)&6)) to make
// the b16 transpose writes bank-conflict-free; reads apply the same XOR.
// ---------------------------------------------------------------------------
__global__ void __launch_bounds__(256) proj_kernel(
    const float* __restrict__ rgb, const float* __restrict__ hsi,
    const unsigned short* __restrict__ Wt,
    unsigned short* __restrict__ Q, unsigned short* __restrict__ K,
    unsigned short* __restrict__ Vt)
{
    __shared__ __align__(16) unsigned short As[64 * LDA];
    __shared__ __align__(16) unsigned short Ws[128 * LDA];

    const int which = blockIdx.y;                 // 0: QK, 1: V
    const int b    = blockIdx.x / 25;
    const int n0   = (blockIdx.x % 25) * 64;
    const int tid  = threadIdx.x;
    const int wv_  = tid >> 6;
    const int lane = tid & 63;
    const int l16  = lane & 15, quad = lane >> 4;

    const float* __restrict__ src = which ? hsi : rgb;
    const unsigned short* __restrict__ wbase = Wt + (which ? (size_t)2 * HCH * CIN : 0);
    const int nW = which ? 1 : 2;

    f32x4 acc[2][4];
    #pragma unroll
    for (int t = 0; t < 2; ++t)
        #pragma unroll
        for (int nt = 0; nt < 4; ++nt)
            #pragma unroll
            for (int r = 0; r < 4; ++r) acc[t][nt][r] = 0.f;

    const int cc = tid >> 2;           // 0..63 channel row (staging)
    const int nq = tid & 3;
    const int swz = cc >> 3;           // channel chunk 0..7
    const int clo = cc & 7;
    const int swzr = (l16 >> 1) & 6;   // read-side XOR (row = wv_*16+l16; wv_*16 ≡ 0 mod 8)

    for (int c0 = 0; c0 < CIN; c0 += 64) {
        __syncthreads();
        {   // token tile transpose f32 -> bf16, [n][c] c-minor, chunk-swizzled
            const float* gs = src + ((size_t)b * CIN + c0 + cc) * NTOK + n0;
            #pragma unroll
            for (int rep = 0; rep < 4; ++rep) {
                const int nn4 = rep * 4 + nq;
                const float4 a = ((const float4*)gs)[nn4];
                const int n = nn4 * 4;
                const int i01 = ((swz ^ ((n >> 1) & 6)) << 3) + clo;
                const int i23 = ((swz ^ (((n + 2) >> 1) & 6)) << 3) + clo;
                As[(n + 0) * LDA + i01] = f2bf(a.x);
                As[(n + 1) * LDA + i01] = f2bf(a.y);
                As[(n + 2) * LDA + i23] = f2bf(a.z);
                As[(n + 3) * LDA + i23] = f2bf(a.w);
            }
        }
        for (int task = tid; task < nW * 512; task += 256) {
            const int row = task >> 3, ch = task & 7;
            *((int4*)(Ws + row * LDA + ch * 8)) =
                *((const int4*)(wbase + (size_t)row * CIN + c0 + ch * 8));
        }
        __syncthreads();

        #pragma unroll
        for (int k0 = 0; k0 < 2; ++k0) {
            const bf16x8 av = *((const bf16x8*)(As + (wv_ * 16 + l16) * LDA + ((k0 * 4 + quad) ^ swzr) * 8));
            if (which == 0) {
                #pragma unroll
                for (int t = 0; t < 2; ++t)
                    #pragma unroll
                    for (int nt = 0; nt < 4; ++nt) {
                        const bf16x8 bv = *((const bf16x8*)(Ws + (t * 64 + nt * 16 + l16) * LDA + k0 * 32 + quad * 8));
                        acc[t][nt] = __builtin_amdgcn_mfma_f32_16x16x32_bf16(av, bv, acc[t][nt], 0, 0, 0);
                    }
            } else {
                #pragma unroll
                for (int nt = 0; nt < 4; ++nt) {
                    const bf16x8 bv = *((const bf16x8*)(Ws + (nt * 16 + l16) * LDA + k0 * 32 + quad * 8));
                    acc[0][nt] = __builtin_amdgcn_mfma_f32_16x16x32_bf16(av, bv, acc[0][nt], 0, 0, 0);
                }
            }
        }
    }

    if (which == 0) {
        const float qscale = 0.18033688f;          // 0.125 / ln(2)
        #pragma unroll
        for (int nt = 0; nt < 4; ++nt) {
            const int h = nt * 16 + l16;
            #pragma unroll
            for (int r = 0; r < 4; ++r) {
                const int n = n0 + wv_ * 16 + quad * 4 + r;
                Q[((size_t)b * NTOK + n) * HCH + h] = f2bf(acc[0][nt][r] * qscale);
                K[((size_t)b * NTOK + n) * HCH + h] = f2bf(acc[1][nt][r]);
            }
        }
    } else {
        // permuted V store: keys n0 + wv_*16 + quad*4 + (0..3)  (g = wv_, q4 = quad)
        // go to positions n0 + (wv_&1)*32 + quad*8 + (wv_>>1)*4 + (0..3)
        const int pbase = n0 + (wv_ & 1) * 32 + quad * 8 + (wv_ >> 1) * 4;
        #pragma unroll
        for (int nt = 0; nt < 4; ++nt) {
            const int h = nt * 16 + l16;
            ushort4 pv;
            pv.x = f2bf(acc[0][nt][0]); pv.y = f2bf(acc[0][nt][1]);
            pv.z = f2bf(acc[0][nt][2]); pv.w = f2bf(acc[0][nt][3]);
            *((ushort4*)(Vt + ((size_t)b * HCH + h) * NTOK + pbase)) = pv;
        }
    }
}

// ---------------------------------------------------------------------------
// Attention: split-Q (verified R6 skeleton) + LDS-staged K/V tiles via
// global_load_lds with a counted-vmcnt double buffer (T3/T4 2-phase).
// LDS tile layout: [64 rows][128 B] with XOR swizzle byte ^= (row&7)<<4,
// applied on the STAGING SOURCE address (gload_lds dest is linear) and on
// the fragment ds_read — involution, so reads see the original elements.
// Per tile each wave issues 4 gload_lds (K:2 + V:2, 16 B/lane); the loop
// issues tile t+1, waits vmcnt(4) (tile t complete, t+1 in flight), raw
// s_barrier, computes, raw s_barrier. The DMA needs no VGPRs, so the
// compiler cannot serialize the prefetch (R1/R4/R6 failure mode).
// ---------------------------------------------------------------------------
__device__ __forceinline__ void attn_stage_tile(
    const unsigned short* __restrict__ Kg, const unsigned short* __restrict__ Vg,
    char* buf, int kt, int wv_, int srow, int scole)
{
    #pragma unroll
    for (int i = 0; i < 2; ++i) {
        const int ck  = i * 4 + wv_;          // chunk 0..7 across waves
        const int row = ck * 8 + srow;        // K: key row / V: h row, 0..63
        const unsigned short* ksrc = Kg + (size_t)(kt * 64 + row) * HCH + scole;
        __builtin_amdgcn_global_load_lds(ksrc, buf + ck * 1024, 16, 0, 0);
        const unsigned short* vsrc = Vg + (size_t)row * NTOK + kt * 64 + scole;
        __builtin_amdgcn_global_load_lds(vsrc, buf + 8192 + ck * 1024, 16, 0, 0);
    }
}

__device__ __forceinline__ void attn_compute_lds(
    const char* kbuf, const char* vbuf, int l16, int quad,
    const bf16x8 (&qa)[2], f32x4 (&o)[4], float& rs)
{
    // ---- fragment reads (swizzled): logical col bytes k0*64+quad*16 ----
    bf16x8 kb[2][4], vb[2][4];
    #pragma unroll
    for (int k0 = 0; k0 < 2; ++k0) {
        const int colb = (k0 * 64 + quad * 16) ^ ((l16 & 7) << 4);
        #pragma unroll
        for (int nt = 0; nt < 4; ++nt) {
            kb[k0][nt] = *((const bf16x8*)(kbuf + (nt * 16 + l16) * 128 + colb));
            vb[k0][nt] = *((const bf16x8*)(vbuf + (nt * 16 + l16) * 128 + colb));
        }
    }

    // ---- S^T = K Q^T : col = q (l16), row = key (quad*4+r) ----
    f32x4 s[4];
    #pragma unroll
    for (int nt = 0; nt < 4; ++nt)
        #pragma unroll
        for (int r = 0; r < 4; ++r) s[nt][r] = 0.f;
    #pragma unroll
    for (int k0 = 0; k0 < 2; ++k0)
        #pragma unroll
        for (int nt = 0; nt < 4; ++nt)
            s[nt] = __builtin_amdgcn_mfma_f32_16x16x32_bf16(kb[k0][nt], qa[k0], s[nt], 0, 0, 0);

    // ---- P = exp2(S^T) in-lane, pack bf16 pairs, accumulate row sums ----
    unsigned dA[4], dB[4];
    #pragma unroll
    for (int nt = 0; nt < 4; ++nt) {
        const float e0 = fast_exp2(s[nt][0]);
        const float e1 = fast_exp2(s[nt][1]);
        const float e2 = fast_exp2(s[nt][2]);
        const float e3 = fast_exp2(s[nt][3]);
        rs += (e0 + e1) + (e2 + e3);
        dA[nt] = cvtpk_bf16(e0, e1);
        dB[nt] = cvtpk_bf16(e2, e3);
    }

    // ---- O += P V (V stored pre-permuted to match this packing) ----
    #pragma unroll
    for (int k0 = 0; k0 < 2; ++k0) {
        union { bf16x8 v; unsigned u[4]; } pu;
        pu.u[0] = dA[k0];
        pu.u[1] = dB[k0];
        pu.u[2] = dA[k0 + 2];
        pu.u[3] = dB[k0 + 2];
        #pragma unroll
        for (int nt = 0; nt < 4; ++nt)
            o[nt] = __builtin_amdgcn_mfma_f32_16x16x32_bf16(pu.v, vb[k0][nt], o[nt], 0, 0, 0);
    }
}

__global__ void __launch_bounds__(256) attn_kernel(
    const unsigned short* __restrict__ Q, const unsigned short* __restrict__ K,
    const unsigned short* __restrict__ Vt, unsigned short* __restrict__ Rt2)
{
    __shared__ __align__(16) char sbuf[2][16384];   // [dbuf][K 8KB | V 8KB]

    const int bx   = blockIdx.x;                // 0..399
    const int b    = 2 * (bx & 7) + (((bx >> 3) >= 25) ? 1 : 0);
    const int qt   = (bx >> 3) % 25;            // 64-query tile
    const int tid  = threadIdx.x;
    const int wv_  = tid >> 6;
    const int lane = tid & 63;
    const int l16  = lane & 15, quad = lane >> 4;

    const unsigned short* Qg = Q  + ((size_t)b * NTOK + qt * 64 + wv_ * 16) * HCH;
    const unsigned short* Kg = K  + (size_t)b * NTOK * HCH;
    const unsigned short* Vg = Vt + (size_t)b * HCH * NTOK;

    // staging source geometry (per lane): row-in-chunk, inverse-swizzled col
    const int srow  = lane >> 3;                        // 0..7
    const int scole = 8 * ((lane & 7) ^ srow);          // source col (elems)

    // Q fragments (B-operand of the swapped QK^T), resident all kernel
    bf16x8 qa[2];
    #pragma unroll
    for (int k0 = 0; k0 < 2; ++k0)
        qa[k0] = *((const bf16x8*)(Qg + (size_t)l16 * HCH + k0 * 32 + quad * 8));

    f32x4 o[4];
    float rs = 0.f;
    #pragma unroll
    for (int nt = 0; nt < 4; ++nt)
        #pragma unroll
        for (int r = 0; r < 4; ++r) o[nt][r] = 0.f;

    // ---- counted-vmcnt double-buffered k-loop over all 25 tiles ----
    attn_stage_tile(Kg, Vg, sbuf[0], 0, wv_, srow, scole);
    int cur = 0;
    for (int kt = 0; kt < 25; ++kt) {
        if (kt + 1 < 25) {
            attn_stage_tile(Kg, Vg, sbuf[cur ^ 1], kt + 1, wv_, srow, scole);
            asm volatile("s_waitcnt vmcnt(4)" ::: "memory");
        } else {
            asm volatile("s_waitcnt vmcnt(0)" ::: "memory");
        }
        __builtin_amdgcn_sched_barrier(0);
        __builtin_amdgcn_s_barrier();
        __builtin_amdgcn_sched_barrier(0);
        attn_compute_lds(sbuf[cur], sbuf[cur] + 8192, l16, quad, qa, o, rs);
        __builtin_amdgcn_sched_barrier(0);
        __builtin_amdgcn_s_barrier();
        cur ^= 1;
    }

    // ---- complete row sums (q = l16) across the 4 quads ----
    rs += __shfl_xor(rs, 16);
    rs += __shfl_xor(rs, 32);
    // redistribute to o's q layout (q = quad*4 + r): source lanes 0..15
    float rsq[4];
    #pragma unroll
    for (int r = 0; r < 4; ++r) rsq[r] = __shfl(rs, quad * 4 + r);

    // ---- direct output: Rt2[b][t=qt][h=nt*16+l16][j=wv_*16+quad*4+r] ----
    unsigned short* Rg = Rt2 + ((size_t)(b * 25 + qt)) * HCH * HCH;
    #pragma unroll
    for (int nt = 0; nt < 4; ++nt) {
        ushort4 pk;
        pk.x = f2bf(o[nt][0] / rsq[0]);
        pk.y = f2bf(o[nt][1] / rsq[1]);
        pk.z = f2bf(o[nt][2] / rsq[2]);
        pk.w = f2bf(o[nt][3] / rsq[3]);
        *((ushort4*)(Rg + (size_t)(nt * 16 + l16) * HCH + wv_ * 16 + quad * 4)) = pk;
    }
}

// ---------------------------------------------------------------------------
// Output projection: out[b][c][h*25+t] = sum_j wo[j][c] * Rt2[b][t][h][j]
// Grid (16 b, 8 c-tiles, 25 n-tiles): one 64x64 output tile per block.
// ---------------------------------------------------------------------------
__global__ void __launch_bounds__(256) outproj_kernel(
    const unsigned short* __restrict__ Rt2, const unsigned short* __restrict__ WoT,
    float* __restrict__ out)
{
    __shared__ __align__(16) unsigned short Aw[64 * LDA];

    const int b    = blockIdx.x;
    const int ct   = blockIdx.y;
    const int nt64 = blockIdx.z;
    const int tid  = threadIdx.x;
    const int wv_  = tid >> 6;
    const int lane = tid & 63;
    const int l16  = lane & 15, quad = lane >> 4;

    #pragma unroll
    for (int r = 0; r < 2; ++r) {
        const int task = tid + r * 256;
        const int row = task >> 3, ch = task & 7;
        *((int4*)(Aw + row * LDA + ch * 8)) =
            *((const int4*)(WoT + ((size_t)(ct * 64 + row)) * HCH + ch * 8));
    }
    __syncthreads();

    const int n = nt64 * 64 + wv_ * 16 + l16;
    const int h = n / 25, t = n % 25;
    const unsigned short* bsrc = Rt2 + ((size_t)(b * 25 + t) * HCH + h) * HCH;

    f32x4 acc[4];
    #pragma unroll
    for (int mt = 0; mt < 4; ++mt)
        #pragma unroll
        for (int r = 0; r < 4; ++r) acc[mt][r] = 0.f;

    #pragma unroll
    for (int k0 = 0; k0 < 2; ++k0) {
        const bf16x8 bv = *((const bf16x8*)(bsrc + k0 * 32 + quad * 8));
        #pragma unroll
        for (int mt = 0; mt < 4; ++mt) {
            const bf16x8 av = *((const bf16x8*)(Aw + (mt * 16 + l16) * LDA + k0 * 32 + quad * 8));
            acc[mt] = __builtin_amdgcn_mfma_f32_16x16x32_bf16(av, bv, acc[mt], 0, 0, 0);
        }
    }
    #pragma unroll
    for (int mt = 0; mt < 4; ++mt)
        #pragma unroll
        for (int r = 0; r < 4; ++r)
            out[((size_t)b * CIN + ct * 64 + mt * 16 + quad * 4 + r) * NTOK + n] = acc[mt][r];
}

// ---------------------------------------------------------------------------
extern "C" void kernel_launch(void* const* d_in, const int* in_sizes, int n_in,
                              void* d_out, int out_size, void* d_ws, size_t ws_size,
                              hipStream_t stream)
{
    const float* rgb = (const float*)d_in[0];
    const float* hsi = (const float*)d_in[1];
    const float* wq  = (const float*)d_in[2];
    const float* wk  = (const float*)d_in[3];
    const float* wv  = (const float*)d_in[4];
    const float* wo  = (const float*)d_in[5];
    float* out = (float*)d_out;

    unsigned short* Wt  = (unsigned short*)d_ws;
    unsigned short* WoT = Wt  + (size_t)3 * HCH * CIN;
    unsigned short* Qb  = WoT + (size_t)CIN * HCH;
    unsigned short* Kb  = Qb  + (size_t)NB * NTOK * HCH;
    unsigned short* Vtb = Kb  + (size_t)NB * NTOK * HCH;
    unsigned short* Rt2 = Vtb + (size_t)NB * NTOK * HCH;

    wprep_kernel<<<dim3(64), 256, 0, stream>>>(wq, wk, wv, wo, Wt, WoT);
    proj_kernel<<<dim3(NB * 25, 2), 256, 0, stream>>>(rgb, hsi, Wt, Qb, Kb, Vtb);
    attn_kernel<<<dim3(NB * 25), 256, 0, stream>>>(Qb, Kb, Vtb, Rt2);
    outproj_kernel<<<dim3(NB, 8, 25), 256, 0, stream>>>(Rt2, WoT, out);
}